// Round 1
// 144.060 us; speedup vs baseline: 1.0104x; 1.0104x over previous
//
#include <hip/hip_runtime.h>

// SNN ALIF step, B=32, N=4096, D=8, NE=2048, DE=4.
// K1: per-(chunk,batch) block: spikes + adaptation, LDS-compacted active-source
//     lists written to per-chunk segments with per-chunk counts (NO global
//     atomics, NO counter zero-init needed).
// K2: per (256-col tile, batch) block, 8 waves (512 thr): prefix-merge chunk
//     lists into LDS, 8-way row-split across waves, depth-8 float4 software
//     pipeline over W rows, 256-thread LDS combine, fused membrane epilogue.
//     8 waves/block -> 16 waves/CU (vs 8): K2 is an L3-latency-bound gather
//     (W=96MB is L3-resident, L2-missing), so 2x waves = 2x latency hiding.

#define B_   32
#define N_   4096
#define D_   8
#define NE_  2048
#define DE_  4
#define BN_  (B_ * N_)
#define BNE_ (B_ * NE_)
#define NCH_ 8          // chunks per batch (both int and ext)
#define CI_  512        // int neurons per chunk
#define CE_  256        // ext sources per chunk

// ---------------- K1: spike + compact ----------------
__global__ __launch_bounds__(256) void snn_spike_compact(
    const float* __restrict__ V, const float* __restrict__ a,
    const float* __restrict__ Xd, const float* __restrict__ Xext,
    const float* __restrict__ dmap_int, const float* __restrict__ dmap_ext,
    float* __restrict__ out,
    int* __restrict__ cnt_int, int* __restrict__ cnt_ext,
    unsigned short* __restrict__ list_int, unsigned short* __restrict__ list_ext)
{
#pragma clang fp contract(off)
    // exact op order for th: a 1-ulp difference can flip a spike (absmax 1.0)
    __shared__ unsigned short s_i[CI_];
    __shared__ unsigned short s_e[CE_];
    __shared__ int lc_i, lc_e;
    int tid = threadIdx.x;
    if (tid == 0) { lc_i = 0; lc_e = 0; }
    __syncthreads();

    int b = blockIdx.y;
    int c = blockIdx.x;

    #pragma unroll
    for (int r = 0; r < 2; ++r) {
        int i = c * CI_ + r * 256 + tid;
        int t = b * N_ + i;
        float av = a[t];
        float vv = V[t];
        float th = 1.0f + 1.8f * av;
        float x = (vv - th >= 0.0f) ? 1.0f : 0.0f;
        out[t] = x;                          // X
        out[2 * BN_ + t] = 0.98f * av + x;   // a_new
        int di = 0;
        #pragma unroll
        for (int d = 1; d < D_; ++d)
            if (dmap_int[d * N_ + i] != 0.0f) di = d;
        // Xd_new[0] = X, Xd_new[d>=1] = Xd[d-1]
        float xi = (di == 0) ? x : Xd[(di - 1) * BN_ + t];
        if (xi != 0.0f) {
            int p = atomicAdd(&lc_i, 1);     // LDS atomic only
            s_i[p] = (unsigned short)i;
        }
    }
    {
        int j = c * CE_ + tid;
        int u = b * NE_ + j;
        int de = 0;
        #pragma unroll
        for (int d = 1; d < DE_; ++d)
            if (dmap_ext[d * NE_ + j] != 0.0f) de = d;
        float xe = Xext[de * BNE_ + u];      // external: no shift
        if (xe != 0.0f) {
            int p = atomicAdd(&lc_e, 1);
            s_e[p] = (unsigned short)j;
        }
    }
    __syncthreads();
    // per-chunk segmented output: plain stores, deterministic, no zeroing needed
    if (tid == 0) {
        cnt_int[b * NCH_ + c] = lc_i;
        cnt_ext[b * NCH_ + c] = lc_e;
    }
    for (int k = tid; k < lc_i; k += 256) list_int[b * N_  + c * CI_ + k] = s_i[k];
    for (int k = tid; k < lc_e; k += 256) list_ext[b * NE_ + c * CE_ + k] = s_e[k];
}

// ---------------- K2: gather-accumulate W rows ----------------
__device__ __forceinline__ float4 ld4(const float* p) { return *(const float4*)p; }
__device__ __forceinline__ void add4(float4& a, const float4 w) {
    a.x += w.x; a.y += w.y; a.z += w.z; a.w += w.w;
}

// Accumulate n rows of W (row stride N_) at column j; indices in LDS (sl,
// 16B-aligned). Depth-8 software pipeline: 8-16 float4 loads in flight.
__device__ __forceinline__ void accum_rows(const float* __restrict__ W,
                                           const unsigned short* sl, int n, int j,
                                           float4& acc)
{
    if (n <= 0) return;
    int nf = n & ~7;
    if (nf >= 8) {
        uint4 g = *(const uint4*)(sl);   // 8 indices, LDS broadcast
        float4 p0 = ld4(W + (size_t)(g.x & 0xffff) * N_ + j);
        float4 p1 = ld4(W + (size_t)(g.x >> 16)    * N_ + j);
        float4 p2 = ld4(W + (size_t)(g.y & 0xffff) * N_ + j);
        float4 p3 = ld4(W + (size_t)(g.y >> 16)    * N_ + j);
        float4 p4 = ld4(W + (size_t)(g.z & 0xffff) * N_ + j);
        float4 p5 = ld4(W + (size_t)(g.z >> 16)    * N_ + j);
        float4 p6 = ld4(W + (size_t)(g.w & 0xffff) * N_ + j);
        float4 p7 = ld4(W + (size_t)(g.w >> 16)    * N_ + j);
        for (int k = 8; k < nf; k += 8) {
            uint4 g2 = *(const uint4*)(sl + k);
            float4 q0 = ld4(W + (size_t)(g2.x & 0xffff) * N_ + j);
            float4 q1 = ld4(W + (size_t)(g2.x >> 16)    * N_ + j);
            float4 q2 = ld4(W + (size_t)(g2.y & 0xffff) * N_ + j);
            float4 q3 = ld4(W + (size_t)(g2.y >> 16)    * N_ + j);
            float4 q4 = ld4(W + (size_t)(g2.z & 0xffff) * N_ + j);
            float4 q5 = ld4(W + (size_t)(g2.z >> 16)    * N_ + j);
            float4 q6 = ld4(W + (size_t)(g2.w & 0xffff) * N_ + j);
            float4 q7 = ld4(W + (size_t)(g2.w >> 16)    * N_ + j);
            add4(acc, p0); add4(acc, p1); add4(acc, p2); add4(acc, p3);
            add4(acc, p4); add4(acc, p5); add4(acc, p6); add4(acc, p7);
            p0 = q0; p1 = q1; p2 = q2; p3 = q3;
            p4 = q4; p5 = q5; p6 = q6; p7 = q7;
        }
        add4(acc, p0); add4(acc, p1); add4(acc, p2); add4(acc, p3);
        add4(acc, p4); add4(acc, p5); add4(acc, p6); add4(acc, p7);
    }
    for (int k = nf; k < n; ++k) {
        float4 w = ld4(W + (size_t)sl[k] * N_ + j);
        add4(acc, w);
    }
}

__global__ __launch_bounds__(512, 4) void snn_current(
    const float* __restrict__ W_int, const float* __restrict__ W_ext,
    const float* __restrict__ V, float* __restrict__ out,
    const int* __restrict__ cnt_int, const int* __restrict__ cnt_ext,
    const unsigned short* __restrict__ list_int,
    const unsigned short* __restrict__ list_ext)
{
    __shared__ __align__(16) unsigned short s_int[N_];
    __shared__ __align__(16) unsigned short s_ext[NE_];
    __shared__ float4 s_part[8][64];
    int tid = threadIdx.x;
    int b = blockIdx.y;

    // merge per-chunk segments into contiguous LDS lists (prefix over 8 counts)
    int ci[NCH_], oi[NCH_], ce[NCH_], oe[NCH_];
    int ni = 0, ne = 0;
    #pragma unroll
    for (int c = 0; c < NCH_; ++c) {
        ci[c] = cnt_int[b * NCH_ + c]; oi[c] = ni; ni += ci[c];
        ce[c] = cnt_ext[b * NCH_ + c]; oe[c] = ne; ne += ce[c];
    }
    #pragma unroll
    for (int c = 0; c < NCH_; ++c) {
        for (int k = tid; k < ci[c]; k += 512) s_int[oi[c] + k] = list_int[b * N_  + c * CI_ + k];
        for (int k = tid; k < ce[c]; k += 512) s_ext[oe[c] + k] = list_ext[b * NE_ + c * CE_ + k];
    }
    __syncthreads();

    int w = tid >> 6, lane = tid & 63;
    int j = blockIdx.x * 256 + lane * 4;
    float4 acc = make_float4(0.f, 0.f, 0.f, 0.f);

    // 8-way row-split across the waves; slice starts 8-aligned (16B uint4 reads)
    int qi = ((ni + 63) >> 6) << 3;                  // ceil(ni/8) rounded up to x8
    int si = w * qi;
    accum_rows(W_int, s_int + si, min(ni, si + qi) - si, j, acc);
    int qe = ((ne + 63) >> 6) << 3;
    int se = w * qe;
    accum_rows(W_ext, s_ext + se, min(ne, se + qe) - se, j, acc);

    s_part[w][lane] = acc;
    __syncthreads();

    // combine: s_part viewed as float[8][256]; thread t sums column t.
    // stride-256-float reads: all 256 threads hit distinct banks per step.
    if (tid < 256) {
        const float* spf = (const float*)s_part;
        float cur = 0.0f;
        #pragma unroll
        for (int ww = 0; ww < 8; ++ww) cur += spf[ww * 256 + tid];
        // fused: V_new = ALPHA*V*(1-X) + current   (scalar, fully coalesced)
        int t = b * N_ + blockIdx.x * 256 + tid;
        float v = V[t];
        float x = out[t];                 // X written by K1
        out[BN_ + t] = 0.95f * v * (1.0f - x) + cur;
    }
}

extern "C" void kernel_launch(void* const* d_in, const int* in_sizes, int n_in,
                              void* d_out, int out_size, void* d_ws, size_t ws_size,
                              hipStream_t stream)
{
    const float* V        = (const float*)d_in[0];
    const float* a        = (const float*)d_in[1];
    const float* Xd       = (const float*)d_in[2];
    const float* Xext     = (const float*)d_in[3];
    const float* W_int    = (const float*)d_in[4];
    const float* W_ext    = (const float*)d_in[5];
    const float* dmap_int = (const float*)d_in[6];
    const float* dmap_ext = (const float*)d_in[7];
    float* out = (float*)d_out;

    // ws layout: cnt_int[256] | cnt_ext[256] | list_int[B*N u16] | list_ext[B*NE u16]
    int* cnt_int = (int*)d_ws;
    int* cnt_ext = (int*)((char*)d_ws + 1024);
    unsigned short* list_int = (unsigned short*)((char*)d_ws + 2048);
    unsigned short* list_ext = (unsigned short*)((char*)d_ws + 2048 + (size_t)BN_ * 2);

    dim3 g1(NCH_, B_);
    snn_spike_compact<<<g1, 256, 0, stream>>>(
        V, a, Xd, Xext, dmap_int, dmap_ext, out, cnt_int, cnt_ext, list_int, list_ext);

    dim3 g2(16, B_);   // 16 col-tiles x 32 batches, 8 waves each
    snn_current<<<g2, 512, 0, stream>>>(
        W_int, W_ext, V, out, cnt_int, cnt_ext, list_int, list_ext);
}